// Round 8
// baseline (15129.092 us; speedup 1.0000x reference)
//
#include <hip/hip_runtime.h>
#include <hip/hip_bf16.h>
#include <math.h>

#define EPS_REEIG 0.01f

// ---------------------------------------------------------------------------
// BiMap: Y[b] = W^T X[b] W.  One block per batch element. float4 X loads.
// ---------------------------------------------------------------------------
template<int NIN, int NOUT, int BT>
__global__ void bimap_kernel(const float* __restrict__ X,
                             const float* __restrict__ W,
                             float* __restrict__ Y) {
    __shared__ float Ws[NIN * NOUT];
    __shared__ float T[NIN * NOUT];
    const int b = blockIdx.x;
    const float* Xb = X + (size_t)b * NIN * NIN;

    for (int e = threadIdx.x; e < NIN * NOUT; e += BT) Ws[e] = W[e];
    __syncthreads();

    for (int e = threadIdx.x; e < NIN * NOUT; e += BT) {
        const int i = e / NOUT;
        const int j = e % NOUT;
        float acc = 0.f;
        const float4* xrow = (const float4*)(Xb + (size_t)i * NIN);
#pragma unroll 4
        for (int k4 = 0; k4 < NIN / 4; ++k4) {
            const float4 xv = xrow[k4];
            acc = fmaf(xv.x, Ws[(4 * k4 + 0) * NOUT + j], acc);
            acc = fmaf(xv.y, Ws[(4 * k4 + 1) * NOUT + j], acc);
            acc = fmaf(xv.z, Ws[(4 * k4 + 2) * NOUT + j], acc);
            acc = fmaf(xv.w, Ws[(4 * k4 + 3) * NOUT + j], acc);
        }
        T[e] = acc;
    }
    __syncthreads();

    for (int e = threadIdx.x; e < NOUT * NOUT; e += BT) {
        const int p = e / NOUT;
        const int q = e % NOUT;
        float acc = 0.f;
#pragma unroll 8
        for (int k = 0; k < NIN; ++k) acc += Ws[k * NOUT + p] * T[k * NOUT + q];
        Y[(size_t)b * NOUT * NOUT + e] = acc;
    }
}

// ---------------------------------------------------------------------------
// Wave-synchronous TWO-SIDED cyclic Jacobi, v4 (register/shfl plumbing).
// Lane jl holds row jl (== col jl by symmetry) of A in registers.
// Per round: partner data comes from partner lane's REGISTERS via __shfl;
// LDS is used only as the transpose scratch (scatter + own-row read).
// Rotation params extracted from registers (static cndmask loops, VALU);
// apq symmetrized via one shfl so pair lanes use bitwise-identical c,|s|
// (pairwise-consistent rotations keep V orthogonal by construction).
// DS-cycle model (R7 validated): 774 -> ~610 cy/round, row pitch N+4
// de-aliases the row-read banks (8-way -> ~4-way).
//   FINAL=false: writes R = V*max(lam,eps)*V^T
//   FINAL=true : f=log(max(lam,eps)); out = vech(V f V^T) @ fc_w^T + fc_b
// ---------------------------------------------------------------------------
__device__ __forceinline__ void wave_drain() {
    asm volatile("s_waitcnt lgkmcnt(0)" ::: "memory");
    __builtin_amdgcn_sched_barrier(0);
}

template<int N, int SWEEPS, bool FINAL>
__global__ __launch_bounds__(64) void jacobi2s_v4(
        const float* __restrict__ In, float* __restrict__ Out,
        const float* __restrict__ fc_w, const float* __restrict__ fc_b)
{
    constexpr int GP    = 64 / N;       // matrices per wave
    constexpr int BMASK = N / 4 - 1;    // 16B-block swizzle mask
    constexpr int PITCH = N + 4;        // row pitch: 16B-aligned, banks rotate

    __shared__ float Ab[GP][N * PITCH];
    __shared__ float Wt[FINAL ? 136 : 1][FINAL ? 8 : 1];
    __shared__ float Bs[FINAL ? 8 : 1];

    const int lane  = threadIdx.x & 63;
    const int jl    = lane & (N - 1);     // my row/col/eigvec index
    const int grp   = lane / N;           // matrix slot within wave
    const int gbase = lane & ~(N - 1);    // first lane of my group
    const int mb    = blockIdx.x * GP + grp;

    float* Am = &Ab[grp][0];

    if constexpr (FINAL) {
        for (int t = threadIdx.x; t < 952; t += 64)
            Wt[t / 7][t % 7] = fc_w[(t % 7) * 136 + t / 7];
        if (threadIdx.x < 7) Bs[threadIdx.x] = fc_b[threadIdx.x];
        __syncthreads();
    }

    // ---- load row jl (== col jl) from global, coalesced ----
    float a[N], v[N];
    {
        const float4* row = (const float4*)(In + (size_t)mb * N * N + (size_t)jl * N);
#pragma unroll
        for (int k = 0; k < N / 4; ++k) {
            const float4 q = row[k];
            a[4*k+0] = q.x; a[4*k+1] = q.y; a[4*k+2] = q.z; a[4*k+3] = q.w;
        }
    }
#pragma unroll
    for (int i = 0; i < N; ++i) v[i] = (i == jl) ? 1.f : 0.f;

    // ---- two-sided cyclic Jacobi sweeps ----
    constexpr int m = N - 1;
    for (int sw = 0; sw < SWEEPS; ++sw) {
        for (int r = 0; r < m; ++r) {
            int pp;
            if (jl == m) pp = r;
            else {
                int o = jl - r; if (o < 0) o += m;
                if (o == 0) pp = m;
                else { pp = r + (m - o); if (pp >= m) pp -= m; }
            }
            const int lo   = min(jl, pp);
            const int psrc = gbase + pp;

            // ---- rotation params from registers (VALU extraction) ----
            float d = 0.f, apq_own = 0.f;
#pragma unroll
            for (int i = 0; i < N; ++i) {
                d       = (i == jl) ? a[i] : d;
                apq_own = (i == pp) ? a[i] : apq_own;
            }
            const float dpar = __shfl(d, psrc, 64);
            // symmetrize: both lanes get bitwise-identical apq
            const float apq = 0.5f * (apq_own + __shfl(apq_own, psrc, 64));

            float c = 1.f, s = 0.f;
            if (fabsf(apq) > 1e-36f) {
                const float dlo = (jl == lo) ? d : dpar;
                const float dhi = (jl == lo) ? dpar : d;
                const float tau = (dhi - dlo) / (2.f * apq);
                const float t = copysignf(1.f, tau) /
                                (fabsf(tau) + sqrtf(fmaf(tau, tau, 1.f)));
                c = rsqrtf(fmaf(t, t, 1.f));
                s = t * c;
            }
            const float se = (jl == lo) ? -s : s;

            // ---- col phase: C[:,jl] = c*own + se*partner(regs); scatter ----
#pragma unroll
            for (int i = 0; i < N; ++i) {
                const float pcx = fmaf(c, a[i], se * __shfl(a[i], psrc, 64));
                Am[i * PITCH + (((jl >> 2) ^ (i & BMASK)) << 2) + (jl & 3)] = pcx;
            }
            wave_drain();   // scatter complete before row reads (cross-lane RAW)

            // ---- own row read (b128, swizzled, pitch-rotated banks) ----
            float rr[N];
#pragma unroll
            for (int k = 0; k < N / 4; ++k) {
                const float4 q = *(const float4*)&Am[jl * PITCH + ((k ^ (jl & BMASK)) << 2)];
                rr[4*k+0] = q.x; rr[4*k+1] = q.y; rr[4*k+2] = q.z; rr[4*k+3] = q.w;
            }
            __builtin_amdgcn_sched_barrier(0);

            // ---- row phase: A'[jl,:] = c*row + se*partner-row (regs) ----
#pragma unroll
            for (int i = 0; i < N; ++i)
                a[i] = fmaf(c, rr[i], se * __shfl(rr[i], psrc, 64));

            // ---- V col mix in registers ----
#pragma unroll
            for (int i = 0; i < N; ++i)
                v[i] = fmaf(c, v[i], se * __shfl(v[i], psrc, 64));
            __builtin_amdgcn_sched_barrier(0);
        }

        // ---- sweep-level exit: off-diag Frobenius^2 (diag masked) ----
        {
            float off2 = 0.f;
#pragma unroll
            for (int i = 0; i < N; ++i) {
                const float e = (i == jl) ? 0.f : a[i];
                off2 = fmaf(e, e, off2);
            }
#pragma unroll
            for (int st = 1; st < N; st <<= 1) off2 += __shfl_xor(off2, st, 64);
            if (__all(off2 < 1e-8f)) break;
        }
    }

    // ---- eigenvalue of my column ----
    float lam = 0.f;
#pragma unroll
    for (int i = 0; i < N; ++i) lam = (i == jl) ? a[i] : lam;

    if constexpr (!FINAL) {
        // ---- ReEig: R = Vt Vt^T with Vt = V*sqrt(max(lam,eps)) ----
        const float sc = sqrtf(fmaxf(lam, EPS_REEIG));
        // store Vt col jl (swizzled b128, col-major)
#pragma unroll
        for (int k = 0; k < N / 4; ++k) {
            float4 q;
            q.x = v[4*k+0]*sc; q.y = v[4*k+1]*sc; q.z = v[4*k+2]*sc; q.w = v[4*k+3]*sc;
            *(float4*)&Am[jl * PITCH + ((k ^ (jl & BMASK)) << 2)] = q;
        }
        wave_drain();

        float acc[N];
#pragma unroll
        for (int i = 0; i < N; ++i) acc[i] = 0.f;
        for (int k = 0; k < N; ++k) {
            const float w = Am[k * PITCH + (((jl >> 2) ^ (k & BMASK)) << 2) + (jl & 3)];
#pragma unroll
            for (int t = 0; t < N / 4; ++t) {
                const float4 lk = *(const float4*)&Am[k * PITCH + ((t ^ (k & BMASK)) << 2)];
                acc[4*t+0] = fmaf(lk.x, w, acc[4*t+0]);
                acc[4*t+1] = fmaf(lk.y, w, acc[4*t+1]);
                acc[4*t+2] = fmaf(lk.z, w, acc[4*t+2]);
                acc[4*t+3] = fmaf(lk.w, w, acc[4*t+3]);
            }
        }
        float4* orow = (float4*)(Out + (size_t)mb * N * N + (size_t)jl * N);
#pragma unroll
        for (int k = 0; k < N / 4; ++k) {
            float4 q; q.x = acc[4*k]; q.y = acc[4*k+1]; q.z = acc[4*k+2]; q.w = acc[4*k+3];
            orow[k] = q;
        }
    } else {
        // ---- LogEig + vech + FC (N=16): lane jl owns eigvec jl, weight f ----
        const float f = logf(fmaxf(lam, EPS_REEIG));

        float q[7];
#pragma unroll
        for (int c = 0; c < 7; ++c) q[c] = 0.f;
#pragma unroll
        for (int i = 0; i < N; ++i) {
#pragma unroll
            for (int j = i; j < N; ++j) {
                const int idx = 16 * i - (i * (i + 1)) / 2 + j;  // vech (triu row-major)
                const float o = v[i] * v[j];
#pragma unroll
                for (int c = 0; c < 7; ++c) q[c] = fmaf(o, Wt[idx][c], q[c]);
            }
        }
#pragma unroll
        for (int c = 0; c < 7; ++c) q[c] *= f;
#pragma unroll
        for (int st = 1; st < N; st <<= 1) {
#pragma unroll
            for (int c = 0; c < 7; ++c) q[c] += __shfl_xor(q[c], st, 64);
        }
#pragma unroll
        for (int c = 0; c < 7; ++c)
            if (jl == c) Out[(size_t)mb * 7 + c] = q[c] + Bs[c];
    }
}

// ---------------------------------------------------------------------------
extern "C" void kernel_launch(void* const* d_in, const int* in_sizes, int n_in,
                              void* d_out, int out_size, void* d_ws, size_t ws_size,
                              hipStream_t stream) {
    const float* x    = (const float*)d_in[0];   // [B,128,128]
    const float* W1   = (const float*)d_in[1];   // [128,64]
    const float* W2   = (const float*)d_in[2];   // [64,32]
    const float* W3   = (const float*)d_in[3];   // [32,16]
    const float* fc_w = (const float*)d_in[4];   // [7,136]
    const float* fc_b = (const float*)d_in[5];   // [7]
    float* out = (float*)d_out;                  // [B,7]

    const int B = in_sizes[0] / (128 * 128);

    float* y1 = (float*)d_ws;                    // [B,64,64]
    float* y2 = y1 + (size_t)B * 64 * 64;        // [B,32,32]
    float* y3 = y2 + (size_t)B * 32 * 32;        // [B,16,16]

    bimap_kernel<128, 64, 256><<<B, 256, 0, stream>>>(x, W1, y1);
    jacobi2s_v4<64, 10, false><<<B, 64, 0, stream>>>(y1, y1, nullptr, nullptr);
    bimap_kernel<64, 32, 256><<<B, 256, 0, stream>>>(y1, W2, y2);
    jacobi2s_v4<32, 9, false><<<B / 2, 64, 0, stream>>>(y2, y2, nullptr, nullptr);
    bimap_kernel<32, 16, 256><<<B, 256, 0, stream>>>(y2, W3, y3);
    jacobi2s_v4<16, 8, true><<<B / 4, 64, 0, stream>>>(y3, out, fc_w, fc_b);
}

// Round 9
// 12930.391 us; speedup vs baseline: 1.1700x; 1.1700x over previous
//
#include <hip/hip_runtime.h>
#include <hip/hip_bf16.h>
#include <math.h>

#define EPS_REEIG 0.01f

// ---------------------------------------------------------------------------
// BiMap: Y[b] = W^T X[b] W.  One block per batch element. float4 X loads.
// ---------------------------------------------------------------------------
template<int NIN, int NOUT, int BT>
__global__ void bimap_kernel(const float* __restrict__ X,
                             const float* __restrict__ W,
                             float* __restrict__ Y) {
    __shared__ float Ws[NIN * NOUT];
    __shared__ float T[NIN * NOUT];
    const int b = blockIdx.x;
    const float* Xb = X + (size_t)b * NIN * NIN;

    for (int e = threadIdx.x; e < NIN * NOUT; e += BT) Ws[e] = W[e];
    __syncthreads();

    for (int e = threadIdx.x; e < NIN * NOUT; e += BT) {
        const int i = e / NOUT;
        const int j = e % NOUT;
        float acc = 0.f;
        const float4* xrow = (const float4*)(Xb + (size_t)i * NIN);
#pragma unroll 4
        for (int k4 = 0; k4 < NIN / 4; ++k4) {
            const float4 xv = xrow[k4];
            acc = fmaf(xv.x, Ws[(4 * k4 + 0) * NOUT + j], acc);
            acc = fmaf(xv.y, Ws[(4 * k4 + 1) * NOUT + j], acc);
            acc = fmaf(xv.z, Ws[(4 * k4 + 2) * NOUT + j], acc);
            acc = fmaf(xv.w, Ws[(4 * k4 + 3) * NOUT + j], acc);
        }
        T[e] = acc;
    }
    __syncthreads();

    for (int e = threadIdx.x; e < NOUT * NOUT; e += BT) {
        const int p = e / NOUT;
        const int q = e % NOUT;
        float acc = 0.f;
#pragma unroll 8
        for (int k = 0; k < NIN; ++k) acc += Ws[k * NOUT + p] * T[k * NOUT + q];
        Y[(size_t)b * NOUT * NOUT + e] = acc;
    }
}

// ---------------------------------------------------------------------------
// Wave-synchronous TWO-SIDED Jacobi, v5: XOR pairing, LDS-free sweep loop.
//  - Round k (k=1..N-1) pairs column i with i^k: every pair hit once per
//    sweep (k = i^j), partner is always shfl_xor(k). No tournament slots.
//  - Col phase: pc = c*a + se*shfl_xor(a,k)          (64 bperm + VALU)
//  - Row phase: a'[i] = c_i*pc[i] + se_i*pc[i^k]:
//      pc[i^k] via in-register XOR butterfly (6 uniform-branched bit-stages
//      of static swaps -- VALU, replaces v3's 256-DS-cy LDS transpose);
//      (c_i, se_i) via v_readlane from lane i (VALU; N<64 uses shfl).
//  - Diag tracked in-register: d' = d -/+ t*apq (GVL closed form) -- used
//    ONLY for rotation params; final eigenvalues read from converged a[].
//    Rotations stay exactly orthogonal (pair-consistent c,s) => V exact.
//  - LDS appears only in the reconstruction epilogue (v4's, proven).
// R8 lesson encoded: PITCH=N+4 b128 row reads are 16-way conflicted; here
// the sweep loop has NO LDS at all, so no pitch to get wrong.
//   FINAL=false: writes R = V*max(lam,eps)*V^T
//   FINAL=true : f=log(max(lam,eps)); out = vech(V f V^T) @ fc_w^T + fc_b
// ---------------------------------------------------------------------------
__device__ __forceinline__ void wave_drain() {
    asm volatile("s_waitcnt lgkmcnt(0)" ::: "memory");
    __builtin_amdgcn_sched_barrier(0);
}

template<int N, int SWEEPS, bool FINAL>
__global__ __launch_bounds__(64) void jacobi_xor(
        const float* __restrict__ In, float* __restrict__ Out,
        const float* __restrict__ fc_w, const float* __restrict__ fc_b)
{
    constexpr int GP    = 64 / N;
    constexpr int BMASK = N / 4 - 1;
    constexpr int PITCH = N + 4;        // epilogue-only scratch

    __shared__ float Ab[GP][N * PITCH];
    __shared__ float Wt[FINAL ? 136 : 1][FINAL ? 8 : 1];
    __shared__ float Bs[FINAL ? 8 : 1];

    const int lane  = threadIdx.x & 63;
    const int jl    = lane & (N - 1);
    const int grp   = lane / N;
    const int gbase = lane & ~(N - 1);
    const int mb    = blockIdx.x * GP + grp;

    float* Am = &Ab[grp][0];

    if constexpr (FINAL) {
        for (int t = threadIdx.x; t < 952; t += 64)
            Wt[t / 7][t % 7] = fc_w[(t % 7) * 136 + t / 7];
        if (threadIdx.x < 7) Bs[threadIdx.x] = fc_b[threadIdx.x];
        __syncthreads();
    }

    // ---- load row jl (== col jl by symmetry), coalesced ----
    float a[N], v[N];
    {
        const float4* row = (const float4*)(In + (size_t)mb * N * N + (size_t)jl * N);
#pragma unroll
        for (int k = 0; k < N / 4; ++k) {
            const float4 q = row[k];
            a[4*k+0] = q.x; a[4*k+1] = q.y; a[4*k+2] = q.z; a[4*k+3] = q.w;
        }
    }
#pragma unroll
    for (int i = 0; i < N; ++i) v[i] = (i == jl) ? 1.f : 0.f;

    // ---- diagonal tracked in-register ----
    float dg = 0.f;
#pragma unroll
    for (int i = 0; i < N; ++i) dg = (i == jl) ? a[i] : dg;

    // ---- sweeps: rounds k = 1..N-1 (XOR matchings) ----
    for (int sw = 0; sw < SWEEPS; ++sw) {
        for (int k = 1; k < N; ++k) {
            const int pidx = jl ^ k;

            // a_pq = my column's element at row pidx (static select chain)
            float apq_own = 0.f;
#pragma unroll
            for (int i = 0; i < N; ++i) apq_own = (i == pidx) ? a[i] : apq_own;
            const float apq  = 0.5f * (apq_own + __shfl_xor(apq_own, k, 64));
            const float dpar = __shfl_xor(dg, k, 64);
            const bool  amlo = jl < pidx;

            float c = 1.f, s = 0.f, tt = 0.f;
            if (fabsf(apq) > 1e-36f) {
                const float dlo = amlo ? dg : dpar;
                const float dhi = amlo ? dpar : dg;
                const float tau = (dhi - dlo) / (2.f * apq);
                tt = copysignf(1.f, tau) /
                     (fabsf(tau) + sqrtf(fmaf(tau, tau, 1.f)));
                c = rsqrtf(fmaf(tt, tt, 1.f));
                s = tt * c;
            }
            const float se = amlo ? -s : s;

            // ---- col phase (in place): a := C[:,jl] = c*a + se*partner ----
#pragma unroll
            for (int i = 0; i < N; ++i) {
                const float t = __shfl_xor(a[i], k, 64);
                a[i] = fmaf(c, a[i], se * t);
            }
            // diag update (GVL): d_lo' = d_lo - t*apq ; d_hi' = d_hi + t*apq
            dg = fmaf(amlo ? -tt : tt, apq, dg);

            // ---- pcs[i] = pc[i^k] via XOR butterfly (uniform branches) ----
            float pcs[N];
#pragma unroll
            for (int i = 0; i < N; ++i) pcs[i] = a[i];
#pragma unroll
            for (int b = 1; b < N; b <<= 1) {
                if (k & b) {
#pragma unroll
                    for (int i = 0; i < N; ++i) {
                        if ((i & b) == 0) {
                            const float t = pcs[i]; pcs[i] = pcs[i | b]; pcs[i | b] = t;
                        }
                    }
                }
            }

            // ---- row phase: a'[i] = c_i*pc[i] + se_i*pc[i^k] ----
            if constexpr (N == 64) {
#pragma unroll
                for (int i = 0; i < N; ++i) {
                    const float ci = __int_as_float(
                        __builtin_amdgcn_readlane(__float_as_int(c), i));
                    const float si = __int_as_float(
                        __builtin_amdgcn_readlane(__float_as_int(se), i));
                    a[i] = fmaf(ci, a[i], si * pcs[i]);
                }
            } else {
#pragma unroll
                for (int i = 0; i < N; ++i) {
                    const float ci = __shfl(c,  gbase + i, 64);
                    const float si = __shfl(se, gbase + i, 64);
                    a[i] = fmaf(ci, a[i], si * pcs[i]);
                }
            }

            // ---- V col mix ----
#pragma unroll
            for (int i = 0; i < N; ++i) {
                const float t = __shfl_xor(v[i], k, 64);
                v[i] = fmaf(c, v[i], se * t);
            }
        }

        // ---- sweep-level exit: off-diag Frobenius^2 (diag masked) ----
        {
            float off2 = 0.f;
#pragma unroll
            for (int i = 0; i < N; ++i) {
                const float e = (i == jl) ? 0.f : a[i];
                off2 = fmaf(e, e, off2);
            }
#pragma unroll
            for (int st = 1; st < N; st <<= 1) off2 += __shfl_xor(off2, st, 64);
            if (__all(off2 < 1e-8f)) break;
        }
    }

    // ---- true eigenvalue from converged diagonal (NOT dg) ----
    float lam = 0.f;
#pragma unroll
    for (int i = 0; i < N; ++i) lam = (i == jl) ? a[i] : lam;

    if constexpr (!FINAL) {
        // ---- ReEig epilogue (v4's, proven): R = Vt Vt^T ----
        const float sc = sqrtf(fmaxf(lam, EPS_REEIG));
#pragma unroll
        for (int k = 0; k < N / 4; ++k) {
            float4 q;
            q.x = v[4*k+0]*sc; q.y = v[4*k+1]*sc; q.z = v[4*k+2]*sc; q.w = v[4*k+3]*sc;
            *(float4*)&Am[jl * PITCH + ((k ^ (jl & BMASK)) << 2)] = q;
        }
        wave_drain();

        float acc[N];
#pragma unroll
        for (int i = 0; i < N; ++i) acc[i] = 0.f;
        for (int k = 0; k < N; ++k) {
            const float w = Am[k * PITCH + (((jl >> 2) ^ (k & BMASK)) << 2) + (jl & 3)];
#pragma unroll
            for (int t = 0; t < N / 4; ++t) {
                const float4 lk = *(const float4*)&Am[k * PITCH + ((t ^ (k & BMASK)) << 2)];
                acc[4*t+0] = fmaf(lk.x, w, acc[4*t+0]);
                acc[4*t+1] = fmaf(lk.y, w, acc[4*t+1]);
                acc[4*t+2] = fmaf(lk.z, w, acc[4*t+2]);
                acc[4*t+3] = fmaf(lk.w, w, acc[4*t+3]);
            }
        }
        float4* orow = (float4*)(Out + (size_t)mb * N * N + (size_t)jl * N);
#pragma unroll
        for (int k = 0; k < N / 4; ++k) {
            float4 q; q.x = acc[4*k]; q.y = acc[4*k+1]; q.z = acc[4*k+2]; q.w = acc[4*k+3];
            orow[k] = q;
        }
    } else {
        // ---- LogEig + vech + FC (N=16, v4's, proven) ----
        const float f = logf(fmaxf(lam, EPS_REEIG));

        float q[7];
#pragma unroll
        for (int c = 0; c < 7; ++c) q[c] = 0.f;
#pragma unroll
        for (int i = 0; i < N; ++i) {
#pragma unroll
            for (int j = i; j < N; ++j) {
                const int idx = 16 * i - (i * (i + 1)) / 2 + j;
                const float o = v[i] * v[j];
#pragma unroll
                for (int c = 0; c < 7; ++c) q[c] = fmaf(o, Wt[idx][c], q[c]);
            }
        }
#pragma unroll
        for (int c = 0; c < 7; ++c) q[c] *= f;
#pragma unroll
        for (int st = 1; st < N; st <<= 1) {
#pragma unroll
            for (int c = 0; c < 7; ++c) q[c] += __shfl_xor(q[c], st, 64);
        }
#pragma unroll
        for (int c = 0; c < 7; ++c)
            if (jl == c) Out[(size_t)mb * 7 + c] = q[c] + Bs[c];
    }
}

// ---------------------------------------------------------------------------
extern "C" void kernel_launch(void* const* d_in, const int* in_sizes, int n_in,
                              void* d_out, int out_size, void* d_ws, size_t ws_size,
                              hipStream_t stream) {
    const float* x    = (const float*)d_in[0];   // [B,128,128]
    const float* W1   = (const float*)d_in[1];   // [128,64]
    const float* W2   = (const float*)d_in[2];   // [64,32]
    const float* W3   = (const float*)d_in[3];   // [32,16]
    const float* fc_w = (const float*)d_in[4];   // [7,136]
    const float* fc_b = (const float*)d_in[5];   // [7]
    float* out = (float*)d_out;                  // [B,7]

    const int B = in_sizes[0] / (128 * 128);

    float* y1 = (float*)d_ws;                    // [B,64,64]
    float* y2 = y1 + (size_t)B * 64 * 64;        // [B,32,32]
    float* y3 = y2 + (size_t)B * 32 * 32;        // [B,16,16]

    bimap_kernel<128, 64, 256><<<B, 256, 0, stream>>>(x, W1, y1);
    jacobi_xor<64, 12, false><<<B, 64, 0, stream>>>(y1, y1, nullptr, nullptr);
    bimap_kernel<64, 32, 256><<<B, 256, 0, stream>>>(y1, W2, y2);
    jacobi_xor<32, 10, false><<<B / 2, 64, 0, stream>>>(y2, y2, nullptr, nullptr);
    bimap_kernel<32, 16, 256><<<B, 256, 0, stream>>>(y2, W3, y3);
    jacobi_xor<16, 9, true><<<B / 4, 64, 0, stream>>>(y3, out, fc_w, fc_b);
}

// Round 10
// 9250.406 us; speedup vs baseline: 1.6355x; 1.3978x over previous
//
#include <hip/hip_runtime.h>
#include <hip/hip_bf16.h>
#include <math.h>

#define EPS_REEIG 0.01f

// ---------------------------------------------------------------------------
// BiMap v2: Y[b] = W^T X[b] W, register-tiled.
// Phase T = X*W: thread owns 1 col x RPT rows, 4-row register blocking
//   -> 1 Ws LDS read per 4 FMA (was 1:1).
// Phase Y = W^T*T: thread owns a TTxTT output tile; consecutive-element
//   reads get fused to ds_read_b128 by the compiler -> DS/FMA <= 1/2.
// ---------------------------------------------------------------------------
template<int NIN, int NOUT, int BT>
__global__ __launch_bounds__(BT) void bimap_v2(
        const float* __restrict__ X, const float* __restrict__ W,
        float* __restrict__ Y) {
    constexpr int IG  = BT / NOUT;       // row-groups
    constexpr int RPT = NIN / IG;        // rows per thread
    constexpr int CH  = (RPT >= 4) ? 4 : RPT;
    constexpr int TT  = NOUT / 16;       // output tile dim (4 / 2 / 1)

    __shared__ float Ws[NIN * NOUT];
    __shared__ float T[NIN * NOUT];
    const int b = blockIdx.x;
    const float* Xb = X + (size_t)b * NIN * NIN;

    for (int e = threadIdx.x; e < NIN * NOUT; e += BT) Ws[e] = W[e];
    __syncthreads();

    // ---- T = X * W ----
    {
        const int jj = threadIdx.x % NOUT;
        const int ig = threadIdx.x / NOUT;
        for (int ic = 0; ic < RPT; ic += CH) {
            const int i0 = ig * RPT + ic;
            float acc[CH];
#pragma unroll
            for (int r = 0; r < CH; ++r) acc[r] = 0.f;
            for (int k4 = 0; k4 < NIN / 4; ++k4) {
                float4 xv[CH];
#pragma unroll
                for (int r = 0; r < CH; ++r)
                    xv[r] = *(const float4*)(Xb + (size_t)(i0 + r) * NIN + 4 * k4);
#pragma unroll
                for (int kk = 0; kk < 4; ++kk) {
                    const float w = Ws[(4 * k4 + kk) * NOUT + jj];
#pragma unroll
                    for (int r = 0; r < CH; ++r)
                        acc[r] = fmaf(((const float*)&xv[r])[kk], w, acc[r]);
                }
            }
#pragma unroll
            for (int r = 0; r < CH; ++r) T[(i0 + r) * NOUT + jj] = acc[r];
        }
    }
    __syncthreads();

    // ---- Y = W^T * T ----
    {
        const int p0 = (threadIdx.x / 16) * TT;
        const int q0 = (threadIdx.x % 16) * TT;
        float acc[TT][TT];
#pragma unroll
        for (int p = 0; p < TT; ++p)
#pragma unroll
            for (int q = 0; q < TT; ++q) acc[p][q] = 0.f;
        for (int k = 0; k < NIN; ++k) {
            float wp[TT], tq[TT];
#pragma unroll
            for (int p = 0; p < TT; ++p) wp[p] = Ws[k * NOUT + p0 + p];
#pragma unroll
            for (int q = 0; q < TT; ++q) tq[q] = T[k * NOUT + q0 + q];
#pragma unroll
            for (int p = 0; p < TT; ++p)
#pragma unroll
                for (int q = 0; q < TT; ++q)
                    acc[p][q] = fmaf(wp[p], tq[q], acc[p][q]);
        }
        float* Yb = Y + (size_t)b * NOUT * NOUT;
#pragma unroll
        for (int p = 0; p < TT; ++p)
#pragma unroll
            for (int q = 0; q < TT; ++q)
                Yb[(p0 + p) * NOUT + q0 + q] = acc[p][q];
    }
}

// ---------------------------------------------------------------------------
// Wave-synchronous TWO-SIDED cyclic Jacobi, v6 = v3 (R7 champion, proven)
// + threshold-skip rounds.
//  - own column mirrored in registers; pitch-N + 16B XOR swizzle -> b128
//  - transpose trick for the row phase (R6)
//  - sweep-level early exit at off-diag Frobenius^2 < 1e-8 (R7)
//  - NEW: round-level skip when ALL pairs have |apq| < TAU=2e-6 (classical
//    threshold Jacobi). Safe: skipped mass <= 2016*TAU^2 = 8e-9 < 1e-8
//    budget, and the exit criterion still measures the true off^2, so
//    final quality is gated exactly as before. apq is a single shared LDS
//    value per pair -> skip decision is pair-consistent; __all makes it
//    wave-uniform.
// R8/R9 lessons encoded: PITCH stays N (any "de-aliasing" pad makes b128
// row reads 16-way conflicted); full-register plumbing (a+v+pcs ~200 VGPR)
// kills occupancy. v3's uniform-group row read is the static-indexing
// local optimum; its ~22% conflict tax is accepted.
//   FINAL=false: writes R = V*max(lam,eps)*V^T
//   FINAL=true : f=log(max(lam,eps)); out = vech(V f V^T) @ fc_w^T + fc_b
// ---------------------------------------------------------------------------
__device__ __forceinline__ void wave_fence() {
    asm volatile("s_waitcnt lgkmcnt(0)" ::: "memory");
    __builtin_amdgcn_sched_barrier(0);
}

template<int N, int SWEEPS, bool FINAL>
__global__ __launch_bounds__(64) void jacobi2s_v6(
        const float* __restrict__ In, float* __restrict__ Out,
        const float* __restrict__ fc_w, const float* __restrict__ fc_b)
{
    constexpr int GP    = 64 / N;       // matrices per wave
    constexpr int BMASK = N / 4 - 1;    // 16B-block swizzle mask

    __shared__ float Ab[GP][N * N];
    __shared__ float Wt[FINAL ? 136 : 1][FINAL ? 8 : 1];
    __shared__ float Bs[FINAL ? 8 : 1];

    const int lane  = threadIdx.x & 63;
    const int jl    = lane & (N - 1);
    const int grp   = lane / N;
    const int gbase = lane & ~(N - 1);
    const int mb    = blockIdx.x * GP + grp;

    float* Am = &Ab[grp][0];

    if constexpr (FINAL) {
        for (int t = threadIdx.x; t < 952; t += 64)
            Wt[t / 7][t % 7] = fc_w[(t % 7) * 136 + t / 7];
        if (threadIdx.x < 7) Bs[threadIdx.x] = fc_b[threadIdx.x];
    }

    // ---- load row jl (== col jl by symmetry), coalesced ----
    float a[N], v[N];
    {
        const float4* row = (const float4*)(In + (size_t)mb * N * N + (size_t)jl * N);
#pragma unroll
        for (int k = 0; k < N / 4; ++k) {
            const float4 q = row[k];
            a[4*k+0] = q.x; a[4*k+1] = q.y; a[4*k+2] = q.z; a[4*k+3] = q.w;
        }
    }
#pragma unroll
    for (int i = 0; i < N; ++i) v[i] = (i == jl) ? 1.f : 0.f;

    // ---- store col-major swizzled (b128) ----
#pragma unroll
    for (int k = 0; k < N / 4; ++k) {
        float4 q; q.x = a[4*k]; q.y = a[4*k+1]; q.z = a[4*k+2]; q.w = a[4*k+3];
        *(float4*)&Am[jl * N + ((k ^ (jl & BMASK)) << 2)] = q;
    }
    if constexpr (FINAL) __syncthreads();   // Wt ready (one-time)
    wave_fence();

    // ---- two-sided cyclic Jacobi sweeps ----
    constexpr int m = N - 1;
    for (int sw = 0; sw < SWEEPS; ++sw) {
        for (int r = 0; r < m; ++r) {
            int pp;
            if (jl == m) pp = r;
            else {
                int o = jl - r; if (o < 0) o += m;
                if (o == 0) pp = m;
                else { pp = r + (m - o); if (pp >= m) pp -= m; }
            }
            const int lo = min(jl, pp);
            const int hi = jl ^ pp ^ lo;

            // rotation params (swizzled b32 reads; pair reads identical values)
            const float apq  = Am[hi * N + (((lo >> 2) ^ (hi & BMASK)) << 2) + (lo & 3)];

            // ---- threshold skip: all pairs negligible -> free round ----
            if (__all(fabsf(apq) < 2e-6f)) continue;

            const float down = Am[jl * N + (((jl >> 2) ^ (jl & BMASK)) << 2) + (jl & 3)];
            const float dpar = Am[pp * N + (((pp >> 2) ^ (pp & BMASK)) << 2) + (pp & 3)];
            float c = 1.f, s = 0.f;
            if (fabsf(apq) > 1e-36f) {
                const float dlo = (jl == lo) ? down : dpar;
                const float dhi = (jl == lo) ? dpar : down;
                const float tau = (dhi - dlo) / (2.f * apq);
                const float t = copysignf(1.f, tau) /
                                (fabsf(tau) + sqrtf(fmaf(tau, tau, 1.f)));
                c = rsqrtf(fmaf(t, t, 1.f));
                s = t * c;
            }
            const float se = (jl == lo) ? -s : s;

            // ---- col phase: C col jl = c*own + se*partner (b128) ----
            float pc[N];
#pragma unroll
            for (int k = 0; k < N / 4; ++k) {
                const float4 q = *(const float4*)&Am[pp * N + ((k ^ (pp & BMASK)) << 2)];
                pc[4*k+0] = q.x; pc[4*k+1] = q.y; pc[4*k+2] = q.z; pc[4*k+3] = q.w;
            }
#pragma unroll
            for (int i = 0; i < N; ++i) pc[i] = fmaf(c, a[i], se * pc[i]);
            wave_fence();                      // all cols checked out
            // ---- transpose write: C[i][jl] -> row-slot i, elem jl ----
#pragma unroll
            for (int i = 0; i < N; ++i)
                Am[i * N + (((jl >> 2) ^ (i & BMASK)) << 2) + (jl & 3)] = pc[i];
            wave_fence();

            // ---- row phase: rows contiguous now (b128) ----
#pragma unroll
            for (int k = 0; k < N / 4; ++k) {
                const float4 q = *(const float4*)&Am[jl * N + ((k ^ (jl & BMASK)) << 2)];
                a[4*k+0] = q.x; a[4*k+1] = q.y; a[4*k+2] = q.z; a[4*k+3] = q.w;
            }
            float pr[N];
#pragma unroll
            for (int k = 0; k < N / 4; ++k) {
                const float4 q = *(const float4*)&Am[pp * N + ((k ^ (pp & BMASK)) << 2)];
                pr[4*k+0] = q.x; pr[4*k+1] = q.y; pr[4*k+2] = q.z; pr[4*k+3] = q.w;
            }
#pragma unroll
            for (int i = 0; i < N; ++i) a[i] = fmaf(c, a[i], se * pr[i]);
            wave_fence();                      // rows all checked out
            // ---- A' row jl == A' col jl: restore col-major invariant ----
#pragma unroll
            for (int k = 0; k < N / 4; ++k) {
                float4 q; q.x = a[4*k]; q.y = a[4*k+1]; q.z = a[4*k+2]; q.w = a[4*k+3];
                *(float4*)&Am[jl * N + ((k ^ (jl & BMASK)) << 2)] = q;
            }
            // ---- V col mix in registers via shfl ----
            {
                const int psrc = gbase + pp;
#pragma unroll
                for (int i = 0; i < N; ++i) {
                    const float pv = __shfl(v[i], psrc, 64);
                    v[i] = fmaf(c, v[i], se * pv);
                }
            }
            wave_fence();                      // col-major restored for next round
        }

        // ---- sweep-level exit: off-diag Frobenius^2 (diag masked) ----
        {
            float off2 = 0.f;
#pragma unroll
            for (int i = 0; i < N; ++i) {
                const float e = (i == jl) ? 0.f : a[i];
                off2 = fmaf(e, e, off2);
            }
#pragma unroll
            for (int st = 1; st < N; st <<= 1) off2 += __shfl_xor(off2, st, 64);
            if (__all(off2 < 1e-8f)) break;
        }
    }

    const float lam = Am[jl * N + (((jl >> 2) ^ (jl & BMASK)) << 2) + (jl & 3)];

    if constexpr (!FINAL) {
        // ---- ReEig: R = Vt Vt^T with Vt = V*sqrt(max(lam,eps)) ----
        const float sc = sqrtf(fmaxf(lam, EPS_REEIG));
#pragma unroll
        for (int k = 0; k < N / 4; ++k) {
            float4 q;
            q.x = v[4*k+0]*sc; q.y = v[4*k+1]*sc; q.z = v[4*k+2]*sc; q.w = v[4*k+3]*sc;
            *(float4*)&Am[jl * N + ((k ^ (jl & BMASK)) << 2)] = q;
        }
        wave_fence();

        float acc[N];
#pragma unroll
        for (int i = 0; i < N; ++i) acc[i] = 0.f;
        for (int k = 0; k < N; ++k) {
            const float w = Am[k * N + (((jl >> 2) ^ (k & BMASK)) << 2) + (jl & 3)];
#pragma unroll
            for (int t = 0; t < N / 4; ++t) {
                const float4 lk = *(const float4*)&Am[k * N + ((t ^ (k & BMASK)) << 2)];
                acc[4*t+0] = fmaf(lk.x, w, acc[4*t+0]);
                acc[4*t+1] = fmaf(lk.y, w, acc[4*t+1]);
                acc[4*t+2] = fmaf(lk.z, w, acc[4*t+2]);
                acc[4*t+3] = fmaf(lk.w, w, acc[4*t+3]);
            }
        }
        float4* orow = (float4*)(Out + (size_t)mb * N * N + (size_t)jl * N);
#pragma unroll
        for (int k = 0; k < N / 4; ++k) {
            float4 q; q.x = acc[4*k]; q.y = acc[4*k+1]; q.z = acc[4*k+2]; q.w = acc[4*k+3];
            orow[k] = q;
        }
    } else {
        // ---- LogEig + vech + FC (N=16) ----
        const float f = logf(fmaxf(lam, EPS_REEIG));

        float q[7];
#pragma unroll
        for (int c = 0; c < 7; ++c) q[c] = 0.f;
#pragma unroll
        for (int i = 0; i < N; ++i) {
#pragma unroll
            for (int j = i; j < N; ++j) {
                const int idx = 16 * i - (i * (i + 1)) / 2 + j;
                const float o = v[i] * v[j];
#pragma unroll
                for (int c = 0; c < 7; ++c) q[c] = fmaf(o, Wt[idx][c], q[c]);
            }
        }
#pragma unroll
        for (int c = 0; c < 7; ++c) q[c] *= f;
#pragma unroll
        for (int st = 1; st < N; st <<= 1) {
#pragma unroll
            for (int c = 0; c < 7; ++c) q[c] += __shfl_xor(q[c], st, 64);
        }
#pragma unroll
        for (int c = 0; c < 7; ++c)
            if (jl == c) Out[(size_t)mb * 7 + c] = q[c] + Bs[c];
    }
}

// ---------------------------------------------------------------------------
extern "C" void kernel_launch(void* const* d_in, const int* in_sizes, int n_in,
                              void* d_out, int out_size, void* d_ws, size_t ws_size,
                              hipStream_t stream) {
    const float* x    = (const float*)d_in[0];   // [B,128,128]
    const float* W1   = (const float*)d_in[1];   // [128,64]
    const float* W2   = (const float*)d_in[2];   // [64,32]
    const float* W3   = (const float*)d_in[3];   // [32,16]
    const float* fc_w = (const float*)d_in[4];   // [7,136]
    const float* fc_b = (const float*)d_in[5];   // [7]
    float* out = (float*)d_out;                  // [B,7]

    const int B = in_sizes[0] / (128 * 128);

    float* y1 = (float*)d_ws;                    // [B,64,64]
    float* y2 = y1 + (size_t)B * 64 * 64;        // [B,32,32]
    float* y3 = y2 + (size_t)B * 32 * 32;        // [B,16,16]

    bimap_v2<128, 64, 256><<<B, 256, 0, stream>>>(x, W1, y1);
    jacobi2s_v6<64, 10, false><<<B, 64, 0, stream>>>(y1, y1, nullptr, nullptr);
    bimap_v2<64, 32, 256><<<B, 256, 0, stream>>>(y1, W2, y2);
    jacobi2s_v6<32, 9, false><<<B / 2, 64, 0, stream>>>(y2, y2, nullptr, nullptr);
    bimap_v2<32, 16, 256><<<B, 256, 0, stream>>>(y2, W3, y3);
    jacobi2s_v6<16, 8, true><<<B / 4, 64, 0, stream>>>(y3, out, fc_w, fc_b);
}